// Round 6
// baseline (515.554 us; speedup 1.0000x reference)
//
#include <hip/hip_runtime.h>
#include <hip/hip_fp16.h>

#define DI __device__ __forceinline__

typedef __attribute__((ext_vector_type(4))) float f32x4;
typedef __attribute__((ext_vector_type(8))) short s16x8;

DI unsigned short f2h(float f) { return __half_as_ushort(__float2half(f)); }
DI float h2f(unsigned short u) { return __half2float(__ushort_as_half(u)); }

DI void gload16(const void* g, void* l) {
    __builtin_amdgcn_global_load_lds((const __attribute__((address_space(1))) void*)g,
                                     (__attribute__((address_space(3))) void*)l, 16, 0, 0);
}

#define VMC0 asm volatile("s_waitcnt vmcnt(0)" ::: "memory")
#define LGK0 asm volatile("s_waitcnt lgkmcnt(0)" ::: "memory")
#define MFMA16(A, B, C) asm("v_mfma_f32_16x16x32_f16 %0, %1, %2, %0" : "+v"(C) : "v"(A), "v"(B))

// ---------------------------------------------------------------------------
// Fused prep (weight-norm fold + scale fold) + RFF encode, one mega-launch.
// ---------------------------------------------------------------------------
struct PrepArgs {
    const float *qp, *pf, *adj, *Brff;
    const float *v0, *g0, *b0, *v1, *g1, *b1, *v2, *g2, *b2, *v3, *g3, *b3, *v4, *g4, *b4;
    unsigned short *w0, *w1, *w2, *w3;
    float *w4;
    float *bias0, *bias1, *bias2, *bias3, *bias4;
    unsigned short *h0;
};

template <int CIN, int CINPAD>
DI void prep_row(const float* __restrict__ v, const float* __restrict__ g,
                 const float* __restrict__ b, const float* __restrict__ adj,
                 int cout, int use_scale,
                 unsigned short* __restrict__ wout, float* __restrict__ biasout,
                 int ridx, int lane)
{
    const int k = ridx / cout;
    const float* vr = v + (size_t)ridx * CIN;
    constexpr int NV = CINPAD / 64;
    float xv[NV];
    #pragma unroll
    for (int i = 0; i < NV; i++) {
        const int idx = lane + i * 64;
        xv[i] = (CIN == CINPAD || idx < CIN) ? vr[idx] : 0.f;
    }
    float ss = 0.f;
    #pragma unroll
    for (int i = 0; i < NV; i++) ss += xv[i] * xv[i];
    #pragma unroll
    for (int off = 32; off >= 1; off >>= 1) ss += __shfl_xor(ss, off, 64);
    float s = g[ridx] / sqrtf(ss);
    float bias = b[ridx];
    if (use_scale) {
        float d = adj[k * 81];            // adj[k][k]
        d = d > 0.f ? d : 0.f;
        s *= d; bias *= d;                // leaky(z)*s == leaky(z*s), s>=0
    }
    if (lane == 0) biasout[ridx] = bias;
    unsigned short* wr = wout + (size_t)ridx * CINPAD;
    #pragma unroll
    for (int i = 0; i < NV; i++) wr[lane + i * 64] = f2h(xv[i] * s);
}

DI void prep_w4_row(const float* __restrict__ v, const float* __restrict__ g,
                    const float* __restrict__ b, float* __restrict__ wout,
                    float* __restrict__ biasout, int ridx, int lane)
{
    const float x = v[(size_t)ridx * 64 + lane];
    float ss = x * x;
    #pragma unroll
    for (int off = 32; off >= 1; off >>= 1) ss += __shfl_xor(ss, off, 64);
    const float s = g[ridx] / sqrtf(ss);
    if (lane == 0) biasout[ridx] = b[ridx];
    wout[(size_t)ridx * 64 + lane] = x * s;
}

DI void rff_row(const float* __restrict__ qp, const float* __restrict__ pf,
                const float* __restrict__ Brff, unsigned short* __restrict__ h0,
                int row, int lane)
{
    const int c0 = lane * 8;
    const int bb = row / 80;
    const int kj = row - bb * 80;
    unsigned short o[8];
    if (c0 < 480) {
        const float q0 = qp[row * 3 + 0], q1 = qp[row * 3 + 1], q2 = qp[row * 3 + 2];
        float pv[8];
        *reinterpret_cast<float4*>(&pv[0]) = *reinterpret_cast<const float4*>(&pf[(size_t)row * 480 + c0]);
        *reinterpret_cast<float4*>(&pv[4]) = *reinterpret_cast<const float4*>(&pf[(size_t)row * 480 + c0 + 4]);
        const bool issin = (c0 >= 240);
        const int j0 = issin ? (c0 - 240) : c0;
        #pragma unroll
        for (int e = 0; e < 8; e++) {
            const int j = j0 + e;
            float rev = q0 * Brff[j] + q1 * Brff[240 + j] + q2 * Brff[480 + j];
            rev -= floorf(rev);           // v_sin/v_cos take revolutions
            float t = issin ? __builtin_amdgcn_sinf(rev) : __builtin_amdgcn_cosf(rev);
            o[e] = f2h(pv[e] + t);
        }
    } else {
        #pragma unroll
        for (int e = 0; e < 8; e++) o[e] = 0;
    }
    *reinterpret_cast<s16x8*>(&h0[((size_t)kj * 2048 + bb) * 512 + c0]) =
        *reinterpret_cast<const s16x8*>(o);
}

__global__ __launch_bounds__(256) void prep_rff_kernel(PrepArgs a)
{
    const int bid  = blockIdx.x;
    const int wave = threadIdx.x >> 6, lane = threadIdx.x & 63;
    if (bid < 10240)      prep_row<480, 512>(a.v0, a.g0, a.b0, a.adj, 512, 1, a.w0, a.bias0, bid * 4 + wave, lane);
    else if (bid < 15360) prep_row<512, 512>(a.v1, a.g1, a.b1, a.adj, 256, 1, a.w1, a.bias1, (bid - 10240) * 4 + wave, lane);
    else if (bid < 17920) prep_row<256, 256>(a.v2, a.g2, a.b2, a.adj, 128, 1, a.w2, a.bias2, (bid - 15360) * 4 + wave, lane);
    else if (bid < 19200) prep_row<128, 128>(a.v3, a.g3, a.b3, a.adj,  64, 0, a.w3, a.bias3, (bid - 17920) * 4 + wave, lane);
    else if (bid < 19320) prep_w4_row(a.v4, a.g4, a.b4, a.w4, a.bias4, (bid - 19200) * 4 + wave, lane);
    else                  rff_row(a.qp, a.pf, a.Brff, a.h0, (bid - 19320) * 4 + wave, lane);
}

// ---------------------------------------------------------------------------
// Fused L0..L4 mega-kernel. One block = 64 rows (one batch strip) of one joint.
// 512 threads (8 waves). Activations chained in LDS (R0); weights streamed
// through R1 with 1-deep dbuf; stage-0 A (h0) through R2.
//
// LDS (shorts): R0 [0,32768)   h tiles: 8 x [64][64] swizzled
//               R1 [32768,65536) B staging (stage0: 2x[512][32]; st1: 2x[256][64];
//                                st2: 2x[128][64]; st3: 2x[64][64])
//               R2 [65536,73728) stage-0 A dbuf 2x[64][64]
// Total 73728 shorts = 147456 B.
// ---------------------------------------------------------------------------
struct MegaArgs {
    const unsigned short *h0, *w0, *w1, *w2, *w3;
    const float *w4, *bias0, *bias1, *bias2, *bias3, *bias4;
    float* out;
};

DI s16x8 ldsfrag64(const unsigned short* base, int r, int ck) {
    return *reinterpret_cast<const s16x8*>(&base[r * 64 + ((ck ^ (r & 7)) << 3)]);
}

// stage a [R][64] f16 tile from row-major global (row stride CIN f16)
template <int R, int CIN>
DI void stage64(const unsigned short* g, unsigned short* l, int kt, int tid) {
    constexpr int NI = (R * 8) / 512;
    const int w = tid >> 6, lane = tid & 63;
    #pragma unroll
    for (int i = 0; i < NI; i++) {
        const int cl = (w * NI + i) * 64 + lane;
        const int row = cl >> 3, cc = cl & 7;
        const int sc = cc ^ (row & 7);           // inverse-swizzled source
        gload16(g + (size_t)row * CIN + kt * 64 + sc * 8, l + (size_t)(w * NI + i) * 512);
    }
}

// stage a [512][32] f16 sub-tile (w0), swizzle chunk^(row&3)
DI void stage32_512(const unsigned short* g, unsigned short* l, int st, int tid) {
    const int w = tid >> 6, lane = tid & 63;
    #pragma unroll
    for (int i = 0; i < 4; i++) {
        const int cl = (w * 4 + i) * 64 + lane;
        const int row = cl >> 2, cc = cl & 3;
        const int sc = cc ^ (row & 3);
        gload16(g + (size_t)row * 512 + st * 32 + sc * 8, l + (size_t)(w * 4 + i) * 512);
    }
}

__global__ __launch_bounds__(512, 2) void mega_kernel(MegaArgs a)
{
    extern __shared__ __align__(16) unsigned short smem[];
    unsigned short* R0 = smem;
    unsigned short* R1 = smem + 32768;
    unsigned short* R2 = smem + 65536;
    const int tid = threadIdx.x, wid = tid >> 6, lane = tid & 63;
    const int l15 = lane & 15, l4 = lane >> 4;
    const int wn = wid;
    const int bid = blockIdx.x;
    const int swz = (bid & 7) * 320 + (bid >> 3);   // XCD-chunked, bijective (2560%8==0)
    const int kj = swz >> 5;
    const int m0 = (swz & 31) * 64;

    // ---- stage 0: h1 = leaky(h0 @ w0^T + b0). K=512 as 16 sub-tiles of 32.
    {
        const unsigned short* Ab = a.h0 + ((size_t)kj * 2048 + m0) * 512;
        const unsigned short* Bb = a.w0 + (size_t)kj * 512 * 512;
        f32x4 acc[4][4] = {};
        stage64<64, 512>(Ab, R2, 0, tid);          // A tile 0 -> buf 0
        stage32_512(Bb, R1, 0, tid);               // B sub 0 -> buf 0
        for (int s = 0; s < 16; ++s) {
            const int t = s >> 1;
            VMC0;
            __builtin_amdgcn_s_barrier();
            s16x8 af[4], bf[4];
            const unsigned short* pA = R2 + (t & 1) * 4096;
            const unsigned short* pB = R1 + (s & 1) * 16384;
            #pragma unroll
            for (int f = 0; f < 4; f++)
                af[f] = ldsfrag64(pA, f * 16 + l15, (s & 1) * 4 + l4);
            #pragma unroll
            for (int g = 0; g < 4; g++) {
                const int r = wn * 64 + g * 16 + l15;
                bf[g] = *reinterpret_cast<const s16x8*>(&pB[r * 32 + ((l4 ^ (r & 3)) << 3)]);
            }
            if (!(s & 1) && t + 1 < 8) stage64<64, 512>(Ab, R2 + ((t + 1) & 1) * 4096, t + 1, tid);
            if (s + 1 < 16) stage32_512(Bb, R1 + ((s + 1) & 1) * 16384, s + 1, tid);
            LGK0;
            __builtin_amdgcn_sched_barrier(0);
            __builtin_amdgcn_s_setprio(1);
            #pragma unroll
            for (int f = 0; f < 4; f++)
                #pragma unroll
                for (int g = 0; g < 4; g++)
                    MFMA16(af[f], bf[g], acc[f][g]);
            __builtin_amdgcn_s_setprio(0);
            __builtin_amdgcn_s_barrier();
        }
        asm volatile("s_nop 7\n\ts_nop 7" :::);
        float bv[4];
        #pragma unroll
        for (int g = 0; g < 4; g++) bv[g] = a.bias0[kj * 512 + wn * 64 + g * 16 + l15];
        #pragma unroll
        for (int f = 0; f < 4; f++)
            #pragma unroll
            for (int g = 0; g < 4; g++)
                #pragma unroll
                for (int r = 0; r < 4; r++) {
                    float z = acc[f][g][r] + bv[g];
                    z = z >= 0.f ? z : 0.01f * z;
                    const int rr = f * 16 + l4 * 4 + r;
                    const int cc = g * 16 + l15;
                    R0[wn * 4096 + rr * 64 + (((cc >> 3) ^ (rr & 7)) << 3) + (cc & 7)] = f2h(z);
                }
    }
    __syncthreads();

    // ---- stage 1: h2 = leaky(h1 @ w1^T + b1). K=512, 8 tiles.
    {
        const unsigned short* Bb = a.w1 + (size_t)kj * 256 * 512;
        f32x4 acc[4][2] = {};
        stage64<256, 512>(Bb, R1, 0, tid);
        for (int t = 0; t < 8; ++t) {
            VMC0;
            __builtin_amdgcn_s_barrier();
            s16x8 af[4][2], bf[2][2];
            const unsigned short* pA = R0 + t * 4096;
            const unsigned short* pB = R1 + (t & 1) * 16384;
            #pragma unroll
            for (int f = 0; f < 4; f++)
                #pragma unroll
                for (int kk = 0; kk < 2; kk++)
                    af[f][kk] = ldsfrag64(pA, f * 16 + l15, kk * 4 + l4);
            #pragma unroll
            for (int g = 0; g < 2; g++)
                #pragma unroll
                for (int kk = 0; kk < 2; kk++)
                    bf[g][kk] = ldsfrag64(pB, wn * 32 + g * 16 + l15, kk * 4 + l4);
            if (t + 1 < 8) stage64<256, 512>(Bb, R1 + ((t + 1) & 1) * 16384, t + 1, tid);
            LGK0;
            __builtin_amdgcn_sched_barrier(0);
            __builtin_amdgcn_s_setprio(1);
            #pragma unroll
            for (int kk = 0; kk < 2; kk++)
                #pragma unroll
                for (int f = 0; f < 4; f++)
                    #pragma unroll
                    for (int g = 0; g < 2; g++)
                        MFMA16(af[f][kk], bf[g][kk], acc[f][g]);
            __builtin_amdgcn_s_setprio(0);
            __builtin_amdgcn_s_barrier();
        }
        asm volatile("s_nop 7\n\ts_nop 7" :::);
        float bv[2];
        #pragma unroll
        for (int g = 0; g < 2; g++) bv[g] = a.bias1[kj * 256 + wn * 32 + g * 16 + l15];
        #pragma unroll
        for (int f = 0; f < 4; f++)
            #pragma unroll
            for (int g = 0; g < 2; g++)
                #pragma unroll
                for (int r = 0; r < 4; r++) {
                    float z = acc[f][g][r] + bv[g];
                    z = z >= 0.f ? z : 0.01f * z;
                    const int rr = f * 16 + l4 * 4 + r;
                    const int cl = (wn & 1) * 32 + g * 16 + l15;
                    R0[(wn >> 1) * 4096 + rr * 64 + (((cl >> 3) ^ (rr & 7)) << 3) + (cl & 7)] = f2h(z);
                }
    }
    __syncthreads();

    // ---- stage 2: h3 = leaky(h2 @ w2^T + b2). K=256, 4 tiles.
    {
        const unsigned short* Bb = a.w2 + (size_t)kj * 128 * 256;
        f32x4 acc[4] = {};
        stage64<128, 256>(Bb, R1, 0, tid);
        for (int t = 0; t < 4; ++t) {
            VMC0;
            __builtin_amdgcn_s_barrier();
            s16x8 af[4][2], bf[2];
            const unsigned short* pA = R0 + t * 4096;
            const unsigned short* pB = R1 + (t & 1) * 8192;
            #pragma unroll
            for (int f = 0; f < 4; f++)
                #pragma unroll
                for (int kk = 0; kk < 2; kk++)
                    af[f][kk] = ldsfrag64(pA, f * 16 + l15, kk * 4 + l4);
            #pragma unroll
            for (int kk = 0; kk < 2; kk++)
                bf[kk] = ldsfrag64(pB, wn * 16 + l15, kk * 4 + l4);
            if (t + 1 < 4) stage64<128, 256>(Bb, R1 + ((t + 1) & 1) * 8192, t + 1, tid);
            LGK0;
            __builtin_amdgcn_sched_barrier(0);
            __builtin_amdgcn_s_setprio(1);
            #pragma unroll
            for (int kk = 0; kk < 2; kk++)
                #pragma unroll
                for (int f = 0; f < 4; f++)
                    MFMA16(af[f][kk], bf[kk], acc[f]);
            __builtin_amdgcn_s_setprio(0);
            __builtin_amdgcn_s_barrier();
        }
        asm volatile("s_nop 7\n\ts_nop 7" :::);
        const float bv = a.bias2[kj * 128 + wn * 16 + l15];
        #pragma unroll
        for (int f = 0; f < 4; f++)
            #pragma unroll
            for (int r = 0; r < 4; r++) {
                float z = acc[f][r] + bv;
                z = z >= 0.f ? z : 0.01f * z;
                const int rr = f * 16 + l4 * 4 + r;
                const int cl = (wn & 3) * 16 + l15;
                R0[(wn >> 2) * 4096 + rr * 64 + (((cl >> 3) ^ (rr & 7)) << 3) + (cl & 7)] = f2h(z);
            }
    }
    __syncthreads();

    // ---- stage 3: h4 = leaky(h3 @ w3^T + b3). K=128, 2 tiles. waves = 2M x 4N.
    {
        const unsigned short* Bb = a.w3 + (size_t)kj * 64 * 128;
        const int wm = wid >> 2, wn4 = wid & 3;
        f32x4 acc[2] = {};
        stage64<64, 128>(Bb, R1, 0, tid);
        for (int t = 0; t < 2; ++t) {
            VMC0;
            __builtin_amdgcn_s_barrier();
            s16x8 af[2][2], bf[2];
            const unsigned short* pA = R0 + t * 4096;
            const unsigned short* pB = R1 + (t & 1) * 4096;
            #pragma unroll
            for (int f = 0; f < 2; f++)
                #pragma unroll
                for (int kk = 0; kk < 2; kk++)
                    af[f][kk] = ldsfrag64(pA, wm * 32 + f * 16 + l15, kk * 4 + l4);
            #pragma unroll
            for (int kk = 0; kk < 2; kk++)
                bf[kk] = ldsfrag64(pB, wn4 * 16 + l15, kk * 4 + l4);
            if (t == 0) stage64<64, 128>(Bb, R1 + 4096, 1, tid);
            LGK0;
            __builtin_amdgcn_sched_barrier(0);
            __builtin_amdgcn_s_setprio(1);
            #pragma unroll
            for (int kk = 0; kk < 2; kk++)
                #pragma unroll
                for (int f = 0; f < 2; f++)
                    MFMA16(af[f][kk], bf[kk], acc[f]);
            __builtin_amdgcn_s_setprio(0);
            __builtin_amdgcn_s_barrier();
        }
        asm volatile("s_nop 7\n\ts_nop 7" :::);
        const float bv = a.bias3[kj * 64 + wn4 * 16 + l15];
        #pragma unroll
        for (int f = 0; f < 2; f++)
            #pragma unroll
            for (int r = 0; r < 4; r++) {
                float z = acc[f][r] + bv;
                z = z >= 0.f ? z : 0.01f * z;
                const int rr = wm * 32 + f * 16 + l4 * 4 + r;
                const int cl = wn4 * 16 + l15;
                R0[rr * 64 + (((cl >> 3) ^ (rr & 7)) << 3) + (cl & 7)] = f2h(z);
            }
    }
    __syncthreads();

    // ---- stage 4: out = h4 @ w4^T + b4 (f32). One thread per row, 6 outs.
    if (tid < 64) {
        const int row = tid;
        float xv[64];
        #pragma unroll
        for (int ch = 0; ch < 8; ch++) {
            s16x8 v = *reinterpret_cast<const s16x8*>(&R0[row * 64 + ((ch ^ (row & 7)) << 3)]);
            #pragma unroll
            for (int e = 0; e < 8; e++) xv[ch * 8 + e] = h2f((unsigned short)v[e]);
        }
        const float* w4b = a.w4 + kj * 384;
        float* op = a.out + ((size_t)(m0 + row) * 80 + kj) * 6;
        #pragma unroll
        for (int o = 0; o < 6; o++) {
            float sum = a.bias4[kj * 6 + o];
            #pragma unroll
            for (int i = 0; i < 64; i++) sum = fmaf(xv[i], w4b[o * 64 + i], sum);
            op[o] = sum;
        }
    }
}

// ---------------------------------------------------------------------------
extern "C" void kernel_launch(void* const* d_in, const int* in_sizes, int n_in,
                              void* d_out, int out_size, void* d_ws, size_t ws_size,
                              hipStream_t stream)
{
    (void)in_sizes; (void)n_in; (void)out_size; (void)ws_size;
    PrepArgs a;
    a.qp   = (const float*)d_in[0];
    a.pf   = (const float*)d_in[1];
    a.adj  = (const float*)d_in[2];
    a.Brff = (const float*)d_in[3];
    a.v0 = (const float*)d_in[4];  a.g0 = (const float*)d_in[5];  a.b0 = (const float*)d_in[6];
    a.v1 = (const float*)d_in[7];  a.g1 = (const float*)d_in[8];  a.b1 = (const float*)d_in[9];
    a.v2 = (const float*)d_in[10]; a.g2 = (const float*)d_in[11]; a.b2 = (const float*)d_in[12];
    a.v3 = (const float*)d_in[13]; a.g3 = (const float*)d_in[14]; a.b3 = (const float*)d_in[15];
    a.v4 = (const float*)d_in[16]; a.g4 = (const float*)d_in[17]; a.b4 = (const float*)d_in[18];

    char* ws = (char*)d_ws;
    size_t off = 0;
    auto alloc = [&](size_t n) -> void* {
        off = (off + 255) & ~(size_t)255;
        void* p = ws + off;
        off += n;
        return p;
    };
    a.w0 = (unsigned short*)alloc(80ull * 512 * 512 * 2);
    a.w1 = (unsigned short*)alloc(80ull * 256 * 512 * 2);
    a.w2 = (unsigned short*)alloc(80ull * 128 * 256 * 2);
    a.w3 = (unsigned short*)alloc(80ull * 64 * 128 * 2);
    a.w4 = (float*)alloc(80ull * 6 * 64 * 4);
    a.bias0 = (float*)alloc(80ull * 512 * 4);
    a.bias1 = (float*)alloc(80ull * 256 * 4);
    a.bias2 = (float*)alloc(80ull * 128 * 4);
    a.bias3 = (float*)alloc(80ull * 64 * 4);
    a.bias4 = (float*)alloc(80ull * 6 * 4);
    unsigned short* h0 = (unsigned short*)alloc(163840ull * 512 * 2);
    a.h0 = h0;

    MegaArgs m;
    m.h0 = h0; m.w0 = a.w0; m.w1 = a.w1; m.w2 = a.w2; m.w3 = a.w3;
    m.w4 = a.w4; m.bias0 = a.bias0; m.bias1 = a.bias1; m.bias2 = a.bias2;
    m.bias3 = a.bias3; m.bias4 = a.bias4;
    m.out = (float*)d_out;

    (void)hipFuncSetAttribute((const void*)mega_kernel,
                              hipFuncAttributeMaxDynamicSharedMemorySize, 147456);

    prep_rff_kernel<<<60280, 256, 0, stream>>>(a);
    mega_kernel<<<2560, 512, 147456, stream>>>(m);
}

// Round 7
// 393.582 us; speedup vs baseline: 1.3099x; 1.3099x over previous
//
#include <hip/hip_runtime.h>
#include <hip/hip_fp16.h>

#define DI __device__ __forceinline__

typedef __attribute__((ext_vector_type(4))) float f32x4;
typedef __attribute__((ext_vector_type(8))) short s16x8;

DI unsigned short f2h(float f) { return __half_as_ushort(__float2half(f)); }
DI float h2f(unsigned short u) { return __half2float(__ushort_as_half(u)); }

#define MFMA16(A, B, C) asm("v_mfma_f32_16x16x32_f16 %0, %1, %2, %0" : "+v"(C) : "v"(A), "v"(B))

// ---------------------------------------------------------------------------
// Prep: weight-norm fold + diag-scale fold only (RFF moved into mega kernel).
// ---------------------------------------------------------------------------
struct PrepArgs {
    const float *adj;
    const float *v0,*g0,*b0,*v1,*g1,*b1,*v2,*g2,*b2,*v3,*g3,*b3,*v4,*g4,*b4;
    unsigned short *w0,*w1,*w2,*w3;
    float *w4, *bias0,*bias1,*bias2,*bias3,*bias4;
};

template <int CIN, int CINPAD>
DI void prep_row(const float* __restrict__ v, const float* __restrict__ g,
                 const float* __restrict__ b, const float* __restrict__ adj,
                 int cout, int use_scale,
                 unsigned short* __restrict__ wout, float* __restrict__ biasout,
                 int ridx, int lane)
{
    const int k = ridx / cout;
    const float* vr = v + (size_t)ridx * CIN;
    constexpr int NV = CINPAD / 64;
    float xv[NV];
    #pragma unroll
    for (int i = 0; i < NV; i++) {
        const int idx = lane + i * 64;
        xv[i] = (CIN == CINPAD || idx < CIN) ? vr[idx] : 0.f;
    }
    float ss = 0.f;
    #pragma unroll
    for (int i = 0; i < NV; i++) ss += xv[i] * xv[i];
    #pragma unroll
    for (int off = 32; off >= 1; off >>= 1) ss += __shfl_xor(ss, off, 64);
    float s = g[ridx] / sqrtf(ss);
    float bias = b[ridx];
    if (use_scale) {
        float d = adj[k * 81];            // adj[k][k]
        d = d > 0.f ? d : 0.f;
        s *= d; bias *= d;                // leaky(z)*s == leaky(z*s), s>=0
    }
    if (lane == 0) biasout[ridx] = bias;
    unsigned short* wr = wout + (size_t)ridx * CINPAD;
    #pragma unroll
    for (int i = 0; i < NV; i++) wr[lane + i * 64] = f2h(xv[i] * s);
}

DI void prep_w4_row(const float* __restrict__ v, const float* __restrict__ g,
                    const float* __restrict__ b, float* __restrict__ wout,
                    float* __restrict__ biasout, int ridx, int lane)
{
    const float x = v[(size_t)ridx * 64 + lane];
    float ss = x * x;
    #pragma unroll
    for (int off = 32; off >= 1; off >>= 1) ss += __shfl_xor(ss, off, 64);
    const float s = g[ridx] / sqrtf(ss);
    if (lane == 0) biasout[ridx] = b[ridx];
    wout[(size_t)ridx * 64 + lane] = x * s;
}

__global__ __launch_bounds__(256) void prep_kernel(PrepArgs a)
{
    const int bid = blockIdx.x, wave = threadIdx.x >> 6, lane = threadIdx.x & 63;
    if (bid < 10240)      prep_row<480, 512>(a.v0, a.g0, a.b0, a.adj, 512, 1, a.w0, a.bias0, bid * 4 + wave, lane);
    else if (bid < 15360) prep_row<512, 512>(a.v1, a.g1, a.b1, a.adj, 256, 1, a.w1, a.bias1, (bid - 10240) * 4 + wave, lane);
    else if (bid < 17920) prep_row<256, 256>(a.v2, a.g2, a.b2, a.adj, 128, 1, a.w2, a.bias2, (bid - 15360) * 4 + wave, lane);
    else if (bid < 19200) prep_row<128, 128>(a.v3, a.g3, a.b3, a.adj,  64, 0, a.w3, a.bias3, (bid - 17920) * 4 + wave, lane);
    else                  prep_w4_row(a.v4, a.g4, a.b4, a.w4, a.bias4, (bid - 19200) * 4 + wave, lane);
}

// ---------------------------------------------------------------------------
// Mega v2: one block = 64 batch rows of one joint, 512 threads (8 waves).
// LDS = single 64 KB h-buffer (h0->h1->h2->h3->h4 in place, [64][C] with
// chunk^(row&7) XOR swizzle). Weights read per-lane direct to registers
// (16B fragment loads, L2-resident panels). NO barriers inside stages;
// 2 __syncthreads per stage boundary. RFF+add fused in the prologue.
// ---------------------------------------------------------------------------
struct MegaArgs {
    const float *qp, *pf, *Brff;
    const unsigned short *w0, *w1, *w2, *w3;
    const float *w4, *bias0, *bias1, *bias2, *bias3, *bias4;
    float* out;
};

__global__ __launch_bounds__(512, 4) void mega2_kernel(MegaArgs a)
{
    extern __shared__ __align__(16) unsigned short R0[];   // 32768 shorts = 64 KB
    const int tid = threadIdx.x, wid = tid >> 6, lane = tid & 63;
    const int l15 = lane & 15, l4 = lane >> 4;
    const int bid = blockIdx.x;
    const int swz = (bid & 7) * 320 + (bid >> 3);   // XCD-chunked, bijective (2560%8==0)
    const int kj = swz >> 5;
    const int m0 = (swz & 31) * 64;

    // ---- prologue: h0 = pf + RFF(qp)  -> R0 as [64][512] (480 real + 32 zero-pad)
    {
        const int row = tid >> 3;                 // 0..63
        const int tq  = tid & 7;
        const int gr  = (m0 + row) * 80 + kj;     // batch-major global row
        const float q0 = a.qp[gr * 3 + 0], q1 = a.qp[gr * 3 + 1], q2 = a.qp[gr * 3 + 2];
        #pragma unroll
        for (int i = 0; i < 8; i++) {
            const int c0 = tq * 8 + i * 64;       // multiples of 8, 0..504
            unsigned short o[8];
            if (c0 < 480) {
                float pv[8];
                *reinterpret_cast<float4*>(&pv[0]) = *reinterpret_cast<const float4*>(&a.pf[(size_t)gr * 480 + c0]);
                *reinterpret_cast<float4*>(&pv[4]) = *reinterpret_cast<const float4*>(&a.pf[(size_t)gr * 480 + c0 + 4]);
                const bool issin = (c0 >= 240);
                const int j0 = issin ? (c0 - 240) : c0;
                #pragma unroll
                for (int e = 0; e < 8; e++) {
                    const int j = j0 + e;
                    float rev = q0 * a.Brff[j] + q1 * a.Brff[240 + j] + q2 * a.Brff[480 + j];
                    rev -= floorf(rev);           // v_sin/v_cos take revolutions
                    float t = issin ? __builtin_amdgcn_sinf(rev) : __builtin_amdgcn_cosf(rev);
                    o[e] = f2h(pv[e] + t);
                }
            } else {
                #pragma unroll
                for (int e = 0; e < 8; e++) o[e] = 0;
            }
            const int ck = c0 >> 3;
            *reinterpret_cast<s16x8*>(&R0[row * 512 + ((ck ^ (row & 7)) << 3)]) =
                *reinterpret_cast<const s16x8*>(o);
        }
    }
    __syncthreads();

    // ---- stage 0: h1 = leaky(h0 @ w0^T + b0).  N=512 (wave owns 64 cols), K=512.
    {
        const unsigned short* W = a.w0 + (size_t)kj * 512 * 512;
        f32x4 acc[4][4] = {};
        #pragma unroll
        for (int s = 0; s < 16; s++) {            // K-32 steps
            s16x8 af[4], bf[4];
            #pragma unroll
            for (int f = 0; f < 4; f++) {
                const int r = f * 16 + l15;
                af[f] = *reinterpret_cast<const s16x8*>(&R0[r * 512 + (((s * 4 + l4) ^ (r & 7)) << 3)]);
            }
            #pragma unroll
            for (int g = 0; g < 4; g++)
                bf[g] = *reinterpret_cast<const s16x8*>(&W[(size_t)(wid * 64 + g * 16 + l15) * 512 + s * 32 + l4 * 8]);
            #pragma unroll
            for (int f = 0; f < 4; f++)
                #pragma unroll
                for (int g = 0; g < 4; g++)
                    MFMA16(af[f], bf[g], acc[f][g]);
        }
        __syncthreads();                          // all h0 reads done
        asm volatile("s_nop 7\n\ts_nop 7" :::);
        float bv[4];
        #pragma unroll
        for (int g = 0; g < 4; g++) bv[g] = a.bias0[kj * 512 + wid * 64 + g * 16 + l15];
        #pragma unroll
        for (int f = 0; f < 4; f++)
            #pragma unroll
            for (int g = 0; g < 4; g++)
                #pragma unroll
                for (int r = 0; r < 4; r++) {
                    float z = acc[f][g][r] + bv[g];
                    z = z >= 0.f ? z : 0.01f * z;
                    const int rr = f * 16 + l4 * 4 + r;
                    const int cc = wid * 64 + g * 16 + l15;
                    R0[rr * 512 + (((cc >> 3) ^ (rr & 7)) << 3) + (cc & 7)] = f2h(z);
                }
    }
    __syncthreads();

    // ---- stage 1: h2 = leaky(h1 @ w1^T + b1).  N=256 (wave owns 32), K=512.
    {
        const unsigned short* W = a.w1 + (size_t)kj * 256 * 512;
        f32x4 acc[4][2] = {};
        #pragma unroll
        for (int s = 0; s < 16; s++) {
            s16x8 af[4], bf[2];
            #pragma unroll
            for (int f = 0; f < 4; f++) {
                const int r = f * 16 + l15;
                af[f] = *reinterpret_cast<const s16x8*>(&R0[r * 512 + (((s * 4 + l4) ^ (r & 7)) << 3)]);
            }
            #pragma unroll
            for (int g = 0; g < 2; g++)
                bf[g] = *reinterpret_cast<const s16x8*>(&W[(size_t)(wid * 32 + g * 16 + l15) * 512 + s * 32 + l4 * 8]);
            #pragma unroll
            for (int f = 0; f < 4; f++)
                #pragma unroll
                for (int g = 0; g < 2; g++)
                    MFMA16(af[f], bf[g], acc[f][g]);
        }
        __syncthreads();
        asm volatile("s_nop 7\n\ts_nop 7" :::);
        float bv[2];
        #pragma unroll
        for (int g = 0; g < 2; g++) bv[g] = a.bias1[kj * 256 + wid * 32 + g * 16 + l15];
        #pragma unroll
        for (int f = 0; f < 4; f++)
            #pragma unroll
            for (int g = 0; g < 2; g++)
                #pragma unroll
                for (int r = 0; r < 4; r++) {
                    float z = acc[f][g][r] + bv[g];
                    z = z >= 0.f ? z : 0.01f * z;
                    const int rr = f * 16 + l4 * 4 + r;
                    const int cc = wid * 32 + g * 16 + l15;
                    R0[rr * 256 + (((cc >> 3) ^ (rr & 7)) << 3) + (cc & 7)] = f2h(z);
                }
    }
    __syncthreads();

    // ---- stage 2: h3 = leaky(h2 @ w2^T + b2).  N=128 (wave owns 16), K=256.
    {
        const unsigned short* W = a.w2 + (size_t)kj * 128 * 256;
        f32x4 acc[4] = {};
        #pragma unroll
        for (int s = 0; s < 8; s++) {
            s16x8 af[4], bf;
            #pragma unroll
            for (int f = 0; f < 4; f++) {
                const int r = f * 16 + l15;
                af[f] = *reinterpret_cast<const s16x8*>(&R0[r * 256 + (((s * 4 + l4) ^ (r & 7)) << 3)]);
            }
            bf = *reinterpret_cast<const s16x8*>(&W[(size_t)(wid * 16 + l15) * 256 + s * 32 + l4 * 8]);
            #pragma unroll
            for (int f = 0; f < 4; f++)
                MFMA16(af[f], bf, acc[f]);
        }
        __syncthreads();
        asm volatile("s_nop 7\n\ts_nop 7" :::);
        const float bv = a.bias2[kj * 128 + wid * 16 + l15];
        #pragma unroll
        for (int f = 0; f < 4; f++)
            #pragma unroll
            for (int r = 0; r < 4; r++) {
                float z = acc[f][r] + bv;
                z = z >= 0.f ? z : 0.01f * z;
                const int rr = f * 16 + l4 * 4 + r;
                const int cc = wid * 16 + l15;
                R0[rr * 128 + (((cc >> 3) ^ (rr & 7)) << 3) + (cc & 7)] = f2h(z);
            }
    }
    __syncthreads();

    // ---- stage 3: h4 = leaky(h3 @ w3^T + b3).  N=64, K=128. Waves 2M x 4N.
    {
        const unsigned short* W = a.w3 + (size_t)kj * 64 * 128;
        const int wm = wid >> 2, wn4 = wid & 3;
        f32x4 acc[2] = {};
        #pragma unroll
        for (int s = 0; s < 4; s++) {
            s16x8 af[2], bf;
            #pragma unroll
            for (int f = 0; f < 2; f++) {
                const int r = wm * 32 + f * 16 + l15;
                af[f] = *reinterpret_cast<const s16x8*>(&R0[r * 128 + (((s * 4 + l4) ^ (r & 7)) << 3)]);
            }
            bf = *reinterpret_cast<const s16x8*>(&W[(size_t)(wn4 * 16 + l15) * 128 + s * 32 + l4 * 8]);
            #pragma unroll
            for (int f = 0; f < 2; f++)
                MFMA16(af[f], bf, acc[f]);
        }
        __syncthreads();
        asm volatile("s_nop 7\n\ts_nop 7" :::);
        const float bv = a.bias3[kj * 64 + wn4 * 16 + l15];
        #pragma unroll
        for (int f = 0; f < 2; f++)
            #pragma unroll
            for (int r = 0; r < 4; r++) {
                float z = acc[f][r] + bv;
                z = z >= 0.f ? z : 0.01f * z;
                const int rr = wm * 32 + f * 16 + l4 * 4 + r;
                const int cc = wn4 * 16 + l15;
                R0[rr * 64 + (((cc >> 3) ^ (rr & 7)) << 3) + (cc & 7)] = f2h(z);
            }
    }
    __syncthreads();

    // ---- stage 4: out = h4 @ w4^T + b4 (f32, 6 outputs per row).
    if (tid < 64) {
        const int row = tid;
        float xv[64];
        #pragma unroll
        for (int ch = 0; ch < 8; ch++) {
            s16x8 v = *reinterpret_cast<const s16x8*>(&R0[row * 64 + ((ch ^ (row & 7)) << 3)]);
            #pragma unroll
            for (int e = 0; e < 8; e++) xv[ch * 8 + e] = h2f((unsigned short)v[e]);
        }
        const float* w4b = a.w4 + kj * 384;
        float* op = a.out + ((size_t)(m0 + row) * 80 + kj) * 6;
        #pragma unroll
        for (int o = 0; o < 6; o++) {
            float sum = a.bias4[kj * 6 + o];
            #pragma unroll
            for (int i = 0; i < 64; i++) sum = fmaf(xv[i], w4b[o * 64 + i], sum);
            op[o] = sum;
        }
    }
}

// ---------------------------------------------------------------------------
extern "C" void kernel_launch(void* const* d_in, const int* in_sizes, int n_in,
                              void* d_out, int out_size, void* d_ws, size_t ws_size,
                              hipStream_t stream)
{
    (void)in_sizes; (void)n_in; (void)out_size; (void)ws_size;
    PrepArgs a;
    a.adj  = (const float*)d_in[2];
    a.v0 = (const float*)d_in[4];  a.g0 = (const float*)d_in[5];  a.b0 = (const float*)d_in[6];
    a.v1 = (const float*)d_in[7];  a.g1 = (const float*)d_in[8];  a.b1 = (const float*)d_in[9];
    a.v2 = (const float*)d_in[10]; a.g2 = (const float*)d_in[11]; a.b2 = (const float*)d_in[12];
    a.v3 = (const float*)d_in[13]; a.g3 = (const float*)d_in[14]; a.b3 = (const float*)d_in[15];
    a.v4 = (const float*)d_in[16]; a.g4 = (const float*)d_in[17]; a.b4 = (const float*)d_in[18];

    char* ws = (char*)d_ws;
    size_t off = 0;
    auto alloc = [&](size_t n) -> void* {
        off = (off + 255) & ~(size_t)255;
        void* p = ws + off;
        off += n;
        return p;
    };
    a.w0 = (unsigned short*)alloc(80ull * 512 * 512 * 2);
    a.w1 = (unsigned short*)alloc(80ull * 256 * 512 * 2);
    a.w2 = (unsigned short*)alloc(80ull * 128 * 256 * 2);
    a.w3 = (unsigned short*)alloc(80ull * 64 * 128 * 2);
    a.w4 = (float*)alloc(80ull * 6 * 64 * 4);
    a.bias0 = (float*)alloc(80ull * 512 * 4);
    a.bias1 = (float*)alloc(80ull * 256 * 4);
    a.bias2 = (float*)alloc(80ull * 128 * 4);
    a.bias3 = (float*)alloc(80ull * 64 * 4);
    a.bias4 = (float*)alloc(80ull * 6 * 4);

    MegaArgs m;
    m.qp   = (const float*)d_in[0];
    m.pf   = (const float*)d_in[1];
    m.Brff = (const float*)d_in[3];
    m.w0 = a.w0; m.w1 = a.w1; m.w2 = a.w2; m.w3 = a.w3; m.w4 = a.w4;
    m.bias0 = a.bias0; m.bias1 = a.bias1; m.bias2 = a.bias2;
    m.bias3 = a.bias3; m.bias4 = a.bias4;
    m.out = (float*)d_out;

    (void)hipFuncSetAttribute((const void*)mega2_kernel,
                              hipFuncAttributeMaxDynamicSharedMemorySize, 65536);

    prep_kernel<<<19320, 256, 0, stream>>>(a);
    mega2_kernel<<<2560, 512, 65536, stream>>>(m);
}

// Round 8
// 390.882 us; speedup vs baseline: 1.3189x; 1.0069x over previous
//
#include <hip/hip_runtime.h>
#include <hip/hip_fp16.h>

#define DI __device__ __forceinline__

typedef __attribute__((ext_vector_type(4))) float f32x4;
typedef __attribute__((ext_vector_type(8))) _Float16 f16x8;
typedef __attribute__((ext_vector_type(8))) short s16x8;

DI unsigned short f2h(float f) { return __half_as_ushort(__float2half(f)); }
DI float h2f(unsigned short u) { return __half2float(__ushort_as_half(u)); }

#if __has_builtin(__builtin_amdgcn_mfma_f32_16x16x32_f16)
#define MFMA16(A, B, C) (C) = __builtin_amdgcn_mfma_f32_16x16x32_f16((A), (B), (C), 0, 0, 0)
#else
#define MFMA16(A, B, C) asm("v_mfma_f32_16x16x32_f16 %0, %1, %2, %0" : "+v"(C) : "v"(A), "v"(B))
#endif

// ---------------------------------------------------------------------------
// Prep: weight-norm fold + diag-scale fold only (RFF fused into mega kernel).
// ---------------------------------------------------------------------------
struct PrepArgs {
    const float *adj;
    const float *v0,*g0,*b0,*v1,*g1,*b1,*v2,*g2,*b2,*v3,*g3,*b3,*v4,*g4,*b4;
    unsigned short *w0,*w1,*w2,*w3;
    float *w4, *bias0,*bias1,*bias2,*bias3,*bias4;
};

template <int CIN, int CINPAD>
DI void prep_row(const float* __restrict__ v, const float* __restrict__ g,
                 const float* __restrict__ b, const float* __restrict__ adj,
                 int cout, int use_scale,
                 unsigned short* __restrict__ wout, float* __restrict__ biasout,
                 int ridx, int lane)
{
    const int k = ridx / cout;
    const float* vr = v + (size_t)ridx * CIN;
    constexpr int NV = CINPAD / 64;
    float xv[NV];
    #pragma unroll
    for (int i = 0; i < NV; i++) {
        const int idx = lane + i * 64;
        xv[i] = (CIN == CINPAD || idx < CIN) ? vr[idx] : 0.f;
    }
    float ss = 0.f;
    #pragma unroll
    for (int i = 0; i < NV; i++) ss += xv[i] * xv[i];
    #pragma unroll
    for (int off = 32; off >= 1; off >>= 1) ss += __shfl_xor(ss, off, 64);
    float s = g[ridx] / sqrtf(ss);
    float bias = b[ridx];
    if (use_scale) {
        float d = adj[k * 81];            // adj[k][k]
        d = d > 0.f ? d : 0.f;
        s *= d; bias *= d;                // leaky(z)*s == leaky(z*s), s>=0
    }
    if (lane == 0) biasout[ridx] = bias;
    unsigned short* wr = wout + (size_t)ridx * CINPAD;
    #pragma unroll
    for (int i = 0; i < NV; i++) wr[lane + i * 64] = f2h(xv[i] * s);
}

DI void prep_w4_row(const float* __restrict__ v, const float* __restrict__ g,
                    const float* __restrict__ b, float* __restrict__ wout,
                    float* __restrict__ biasout, int ridx, int lane)
{
    const float x = v[(size_t)ridx * 64 + lane];
    float ss = x * x;
    #pragma unroll
    for (int off = 32; off >= 1; off >>= 1) ss += __shfl_xor(ss, off, 64);
    const float s = g[ridx] / sqrtf(ss);
    if (lane == 0) biasout[ridx] = b[ridx];
    wout[(size_t)ridx * 64 + lane] = x * s;
}

__global__ __launch_bounds__(256) void prep_kernel(PrepArgs a)
{
    const int bid = blockIdx.x, wave = threadIdx.x >> 6, lane = threadIdx.x & 63;
    if (bid < 10240)      prep_row<480, 512>(a.v0, a.g0, a.b0, a.adj, 512, 1, a.w0, a.bias0, bid * 4 + wave, lane);
    else if (bid < 15360) prep_row<512, 512>(a.v1, a.g1, a.b1, a.adj, 256, 1, a.w1, a.bias1, (bid - 10240) * 4 + wave, lane);
    else if (bid < 17920) prep_row<256, 256>(a.v2, a.g2, a.b2, a.adj, 128, 1, a.w2, a.bias2, (bid - 15360) * 4 + wave, lane);
    else if (bid < 19200) prep_row<128, 128>(a.v3, a.g3, a.b3, a.adj,  64, 0, a.w3, a.bias3, (bid - 17920) * 4 + wave, lane);
    else                  prep_w4_row(a.v4, a.g4, a.b4, a.w4, a.bias4, (bid - 19200) * 4 + wave, lane);
}

// ---------------------------------------------------------------------------
// Mega v3: identical structure to v2 (one block = 64 batch rows of one joint,
// 512 threads, single 64 KB in-place h-buffer, per-lane register B loads,
// fused RFF prologue) but MFMA via the gfx950 builtin so accumulators live in
// AGPRs natively — no v_accvgpr ping-pong around inline asm.
// ---------------------------------------------------------------------------
struct MegaArgs {
    const float *qp, *pf, *Brff;
    const unsigned short *w0, *w1, *w2, *w3;
    const float *w4, *bias0, *bias1, *bias2, *bias3, *bias4;
    float* out;
};

__global__ __launch_bounds__(512, 4) void mega3_kernel(MegaArgs a)
{
    extern __shared__ __align__(16) unsigned short R0[];   // 32768 shorts = 64 KB
    const int tid = threadIdx.x, wid = tid >> 6, lane = tid & 63;
    const int l15 = lane & 15, l4 = lane >> 4;
    const int bid = blockIdx.x;
    const int swz = (bid & 7) * 320 + (bid >> 3);   // XCD-chunked, bijective (2560%8==0)
    const int kj = swz >> 5;
    const int m0 = (swz & 31) * 64;

    // ---- prologue: h0 = pf + RFF(qp)  -> R0 as [64][512] (480 real + 32 zero-pad)
    {
        const int row = tid >> 3;                 // 0..63
        const int tq  = tid & 7;
        const int gr  = (m0 + row) * 80 + kj;     // batch-major global row
        const float q0 = a.qp[gr * 3 + 0], q1 = a.qp[gr * 3 + 1], q2 = a.qp[gr * 3 + 2];
        #pragma unroll
        for (int i = 0; i < 8; i++) {
            const int c0 = tq * 8 + i * 64;       // multiples of 8, 0..504
            unsigned short o[8];
            if (c0 < 480) {
                float pv[8];
                *reinterpret_cast<float4*>(&pv[0]) = *reinterpret_cast<const float4*>(&a.pf[(size_t)gr * 480 + c0]);
                *reinterpret_cast<float4*>(&pv[4]) = *reinterpret_cast<const float4*>(&a.pf[(size_t)gr * 480 + c0 + 4]);
                const bool issin = (c0 >= 240);
                const int j0 = issin ? (c0 - 240) : c0;
                #pragma unroll
                for (int e = 0; e < 8; e++) {
                    const int j = j0 + e;
                    float rev = q0 * a.Brff[j] + q1 * a.Brff[240 + j] + q2 * a.Brff[480 + j];
                    rev -= floorf(rev);           // v_sin/v_cos take revolutions
                    float t = issin ? __builtin_amdgcn_sinf(rev) : __builtin_amdgcn_cosf(rev);
                    o[e] = f2h(pv[e] + t);
                }
            } else {
                #pragma unroll
                for (int e = 0; e < 8; e++) o[e] = 0;
            }
            const int ck = c0 >> 3;
            *reinterpret_cast<s16x8*>(&R0[row * 512 + ((ck ^ (row & 7)) << 3)]) =
                *reinterpret_cast<const s16x8*>(o);
        }
    }
    __syncthreads();

    // ---- stage 0: h1 = leaky(h0 @ w0^T + b0).  N=512 (wave owns 64 cols), K=512.
    {
        const unsigned short* W = a.w0 + (size_t)kj * 512 * 512;
        f32x4 acc[4][4] = {};
        #pragma unroll
        for (int s = 0; s < 16; s++) {            // K-32 steps
            f16x8 af[4], bf[4];
            #pragma unroll
            for (int f = 0; f < 4; f++) {
                const int r = f * 16 + l15;
                af[f] = *reinterpret_cast<const f16x8*>(&R0[r * 512 + (((s * 4 + l4) ^ (r & 7)) << 3)]);
            }
            #pragma unroll
            for (int g = 0; g < 4; g++)
                bf[g] = *reinterpret_cast<const f16x8*>(&W[(size_t)(wid * 64 + g * 16 + l15) * 512 + s * 32 + l4 * 8]);
            #pragma unroll
            for (int f = 0; f < 4; f++)
                #pragma unroll
                for (int g = 0; g < 4; g++)
                    MFMA16(af[f], bf[g], acc[f][g]);
        }
        __syncthreads();                          // all h0 reads done
        float bv[4];
        #pragma unroll
        for (int g = 0; g < 4; g++) bv[g] = a.bias0[kj * 512 + wid * 64 + g * 16 + l15];
        #pragma unroll
        for (int f = 0; f < 4; f++)
            #pragma unroll
            for (int g = 0; g < 4; g++)
                #pragma unroll
                for (int r = 0; r < 4; r++) {
                    float z = acc[f][g][r] + bv[g];
                    z = z >= 0.f ? z : 0.01f * z;
                    const int rr = f * 16 + l4 * 4 + r;
                    const int cc = wid * 64 + g * 16 + l15;
                    R0[rr * 512 + (((cc >> 3) ^ (rr & 7)) << 3) + (cc & 7)] = f2h(z);
                }
    }
    __syncthreads();

    // ---- stage 1: h2 = leaky(h1 @ w1^T + b1).  N=256 (wave owns 32), K=512.
    {
        const unsigned short* W = a.w1 + (size_t)kj * 256 * 512;
        f32x4 acc[4][2] = {};
        #pragma unroll
        for (int s = 0; s < 16; s++) {
            f16x8 af[4], bf[2];
            #pragma unroll
            for (int f = 0; f < 4; f++) {
                const int r = f * 16 + l15;
                af[f] = *reinterpret_cast<const f16x8*>(&R0[r * 512 + (((s * 4 + l4) ^ (r & 7)) << 3)]);
            }
            #pragma unroll
            for (int g = 0; g < 2; g++)
                bf[g] = *reinterpret_cast<const f16x8*>(&W[(size_t)(wid * 32 + g * 16 + l15) * 512 + s * 32 + l4 * 8]);
            #pragma unroll
            for (int f = 0; f < 4; f++)
                #pragma unroll
                for (int g = 0; g < 2; g++)
                    MFMA16(af[f], bf[g], acc[f][g]);
        }
        __syncthreads();
        float bv[2];
        #pragma unroll
        for (int g = 0; g < 2; g++) bv[g] = a.bias1[kj * 256 + wid * 32 + g * 16 + l15];
        #pragma unroll
        for (int f = 0; f < 4; f++)
            #pragma unroll
            for (int g = 0; g < 2; g++)
                #pragma unroll
                for (int r = 0; r < 4; r++) {
                    float z = acc[f][g][r] + bv[g];
                    z = z >= 0.f ? z : 0.01f * z;
                    const int rr = f * 16 + l4 * 4 + r;
                    const int cc = wid * 32 + g * 16 + l15;
                    R0[rr * 256 + (((cc >> 3) ^ (rr & 7)) << 3) + (cc & 7)] = f2h(z);
                }
    }
    __syncthreads();

    // ---- stage 2: h3 = leaky(h2 @ w2^T + b2).  N=128 (wave owns 16), K=256.
    {
        const unsigned short* W = a.w2 + (size_t)kj * 128 * 256;
        f32x4 acc[4] = {};
        #pragma unroll
        for (int s = 0; s < 8; s++) {
            f16x8 af[4], bf;
            #pragma unroll
            for (int f = 0; f < 4; f++) {
                const int r = f * 16 + l15;
                af[f] = *reinterpret_cast<const f16x8*>(&R0[r * 256 + (((s * 4 + l4) ^ (r & 7)) << 3)]);
            }
            bf = *reinterpret_cast<const f16x8*>(&W[(size_t)(wid * 16 + l15) * 256 + s * 32 + l4 * 8]);
            #pragma unroll
            for (int f = 0; f < 4; f++)
                MFMA16(af[f], bf, acc[f]);
        }
        __syncthreads();
        const float bv = a.bias2[kj * 128 + wid * 16 + l15];
        #pragma unroll
        for (int f = 0; f < 4; f++)
            #pragma unroll
            for (int r = 0; r < 4; r++) {
                float z = acc[f][r] + bv;
                z = z >= 0.f ? z : 0.01f * z;
                const int rr = f * 16 + l4 * 4 + r;
                const int cc = wid * 16 + l15;
                R0[rr * 128 + (((cc >> 3) ^ (rr & 7)) << 3) + (cc & 7)] = f2h(z);
            }
    }
    __syncthreads();

    // ---- stage 3: h4 = leaky(h3 @ w3^T + b3).  N=64, K=128. Waves 2M x 4N.
    {
        const unsigned short* W = a.w3 + (size_t)kj * 64 * 128;
        const int wm = wid >> 2, wn4 = wid & 3;
        f32x4 acc[2] = {};
        #pragma unroll
        for (int s = 0; s < 4; s++) {
            f16x8 af[2], bf;
            #pragma unroll
            for (int f = 0; f < 2; f++) {
                const int r = wm * 32 + f * 16 + l15;
                af[f] = *reinterpret_cast<const f16x8*>(&R0[r * 128 + (((s * 4 + l4) ^ (r & 7)) << 3)]);
            }
            bf = *reinterpret_cast<const f16x8*>(&W[(size_t)(wn4 * 16 + l15) * 128 + s * 32 + l4 * 8]);
            #pragma unroll
            for (int f = 0; f < 2; f++)
                MFMA16(af[f], bf, acc[f]);
        }
        __syncthreads();
        const float bv = a.bias3[kj * 64 + wn4 * 16 + l15];
        #pragma unroll
        for (int f = 0; f < 2; f++)
            #pragma unroll
            for (int r = 0; r < 4; r++) {
                float z = acc[f][r] + bv;
                z = z >= 0.f ? z : 0.01f * z;
                const int rr = wm * 32 + f * 16 + l4 * 4 + r;
                const int cc = wn4 * 16 + l15;
                R0[rr * 64 + (((cc >> 3) ^ (rr & 7)) << 3) + (cc & 7)] = f2h(z);
            }
    }
    __syncthreads();

    // ---- stage 4: out = h4 @ w4^T + b4 (f32, 6 outputs per row).
    if (tid < 64) {
        const int row = tid;
        float xv[64];
        #pragma unroll
        for (int ch = 0; ch < 8; ch++) {
            s16x8 v = *reinterpret_cast<const s16x8*>(&R0[row * 64 + ((ch ^ (row & 7)) << 3)]);
            #pragma unroll
            for (int e = 0; e < 8; e++) xv[ch * 8 + e] = h2f((unsigned short)v[e]);
        }
        const float* w4b = a.w4 + kj * 384;
        float* op = a.out + ((size_t)(m0 + row) * 80 + kj) * 6;
        #pragma unroll
        for (int o = 0; o < 6; o++) {
            float sum = a.bias4[kj * 6 + o];
            #pragma unroll
            for (int i = 0; i < 64; i++) sum = fmaf(xv[i], w4b[o * 64 + i], sum);
            op[o] = sum;
        }
    }
}

// ---------------------------------------------------------------------------
extern "C" void kernel_launch(void* const* d_in, const int* in_sizes, int n_in,
                              void* d_out, int out_size, void* d_ws, size_t ws_size,
                              hipStream_t stream)
{
    (void)in_sizes; (void)n_in; (void)out_size; (void)ws_size;
    PrepArgs a;
    a.adj  = (const float*)d_in[2];
    a.v0 = (const float*)d_in[4];  a.g0 = (const float*)d_in[5];  a.b0 = (const float*)d_in[6];
    a.v1 = (const float*)d_in[7];  a.g1 = (const float*)d_in[8];  a.b1 = (const float*)d_in[9];
    a.v2 = (const float*)d_in[10]; a.g2 = (const float*)d_in[11]; a.b2 = (const float*)d_in[12];
    a.v3 = (const float*)d_in[13]; a.g3 = (const float*)d_in[14]; a.b3 = (const float*)d_in[15];
    a.v4 = (const float*)d_in[16]; a.g4 = (const float*)d_in[17]; a.b4 = (const float*)d_in[18];

    char* ws = (char*)d_ws;
    size_t off = 0;
    auto alloc = [&](size_t n) -> void* {
        off = (off + 255) & ~(size_t)255;
        void* p = ws + off;
        off += n;
        return p;
    };
    a.w0 = (unsigned short*)alloc(80ull * 512 * 512 * 2);
    a.w1 = (unsigned short*)alloc(80ull * 256 * 512 * 2);
    a.w2 = (unsigned short*)alloc(80ull * 128 * 256 * 2);
    a.w3 = (unsigned short*)alloc(80ull * 64 * 128 * 2);
    a.w4 = (float*)alloc(80ull * 6 * 64 * 4);
    a.bias0 = (float*)alloc(80ull * 512 * 4);
    a.bias1 = (float*)alloc(80ull * 256 * 4);
    a.bias2 = (float*)alloc(80ull * 128 * 4);
    a.bias3 = (float*)alloc(80ull * 64 * 4);
    a.bias4 = (float*)alloc(80ull * 6 * 4);

    MegaArgs m;
    m.qp   = (const float*)d_in[0];
    m.pf   = (const float*)d_in[1];
    m.Brff = (const float*)d_in[3];
    m.w0 = a.w0; m.w1 = a.w1; m.w2 = a.w2; m.w3 = a.w3; m.w4 = a.w4;
    m.bias0 = a.bias0; m.bias1 = a.bias1; m.bias2 = a.bias2;
    m.bias3 = a.bias3; m.bias4 = a.bias4;
    m.out = (float*)d_out;

    (void)hipFuncSetAttribute((const void*)mega3_kernel,
                              hipFuncAttributeMaxDynamicSharedMemorySize, 65536);

    prep_kernel<<<19320, 256, 0, stream>>>(a);
    mega3_kernel<<<2560, 512, 65536, stream>>>(m);
}